// Round 1
// baseline (678.069 us; speedup 1.0000x reference)
//
#include <hip/hip_runtime.h>

#ifndef MIN
#define MIN(a,b) ((a)<(b)?(a):(b))
#endif

// ---------------- degree count ----------------
__global__ void k_deg(const int* __restrict__ dst, int E, int* __restrict__ deg) {
    int i = blockIdx.x * blockDim.x + threadIdx.x;
    int stride = gridDim.x * blockDim.x;
    for (; i < E; i += stride) atomicAdd(&deg[dst[i]], 1);
}

// ---------------- inv_deg = 1/(deg+1) ----------------
__global__ void k_invdeg(const int* __restrict__ deg, float* __restrict__ invdeg, int N) {
    int i = blockIdx.x * blockDim.x + threadIdx.x;
    if (i < N) invdeg[i] = 1.0f / (float)(deg[i] + 1);
}

// ---------------- exclusive scan (3-kernel hierarchical) ----------------
__global__ void k_scan1(const int* __restrict__ deg, int* __restrict__ offsets,
                        int* __restrict__ bsum, int N) {
    __shared__ int sm[1024];
    int i = blockIdx.x * 1024 + threadIdx.x;
    int v = (i < N) ? deg[i] : 0;
    sm[threadIdx.x] = v;
    __syncthreads();
    for (int off = 1; off < 1024; off <<= 1) {
        int t = (threadIdx.x >= off) ? sm[threadIdx.x - off] : 0;
        __syncthreads();
        sm[threadIdx.x] += t;
        __syncthreads();
    }
    if (i < N) offsets[i] = sm[threadIdx.x] - v;       // exclusive within block
    if (threadIdx.x == 1023) bsum[blockIdx.x] = sm[1023];
}

__global__ void k_scan2(int* __restrict__ bsum, int nb) {
    __shared__ int sm[256];
    int v = (threadIdx.x < nb) ? bsum[threadIdx.x] : 0;
    sm[threadIdx.x] = v;
    __syncthreads();
    for (int off = 1; off < 256; off <<= 1) {
        int t = (threadIdx.x >= off) ? sm[threadIdx.x - off] : 0;
        __syncthreads();
        sm[threadIdx.x] += t;
        __syncthreads();
    }
    if (threadIdx.x < nb) bsum[threadIdx.x] = sm[threadIdx.x] - v;  // exclusive
}

__global__ void k_scan3(int* __restrict__ offsets, const int* __restrict__ bsum,
                        const int* __restrict__ deg, int N) {
    int i = blockIdx.x * 1024 + threadIdx.x;
    if (i < N) {
        offsets[i] += bsum[blockIdx.x];
        if (i == N - 1) offsets[N] = offsets[i] + deg[i];
    }
}

// ---------------- build CSR adjacency (by dst) ----------------
__global__ void k_build(const int* __restrict__ src, const int* __restrict__ dst, int E,
                        const int* __restrict__ offsets, int* __restrict__ cursor,
                        int* __restrict__ adj) {
    int i = blockIdx.x * blockDim.x + threadIdx.x;
    int stride = gridDim.x * blockDim.x;
    for (; i < E; i += stride) {
        int d = dst[i];
        int p = atomicAdd(&cursor[d], 1);
        adj[offsets[d] + p] = src[i];
    }
}

// ---------------- layer 0 copy ----------------
__global__ void k_copy(const float4* __restrict__ in, float4* __restrict__ out, int n4) {
    int i = blockIdx.x * blockDim.x + threadIdx.x;
    int stride = gridDim.x * blockDim.x;
    for (; i < n4; i += stride) out[i] = in[i];
}

// ---------------- aggregation layer: one wave (64 lanes) per node ----------------
// lane l owns features [2l, 2l+1] as a float2; D = 128 fixed.
__global__ void k_layer(const float* __restrict__ hin, float* __restrict__ hout,
                        const int* __restrict__ adj, const int* __restrict__ offsets,
                        const float* __restrict__ invdeg, int N) {
    int wave = (blockIdx.x * blockDim.x + threadIdx.x) >> 6;
    int lane = threadIdx.x & 63;
    if (wave >= N) return;
    const int node = wave;
    const int beg = offsets[node];
    const int end = offsets[node + 1];
    const float2* __restrict__ hin2 = (const float2*)hin;
    float2 acc = hin2[(size_t)node * 64 + lane];  // self (self-loop)
    for (int e = beg; e < end; ++e) {
        int s = adj[e];
        float2 v = hin2[(size_t)s * 64 + lane];
        acc.x += v.x;
        acc.y += v.y;
    }
    float w = invdeg[node];
    float2 r;
    r.x = acc.x * w;
    r.y = acc.y * w;
    ((float2*)hout)[(size_t)node * 64 + lane] = r;
}

extern "C" void kernel_launch(void* const* d_in, const int* in_sizes, int n_in,
                              void* d_out, int out_size, void* d_ws, size_t ws_size,
                              hipStream_t stream) {
    const float* x = (const float*)d_in[0];
    const int* ei = (const int*)d_in[1];
    const int N = in_sizes[0] / 128;   // D = 128
    const int E = in_sizes[1] / 2;
    const int* src = ei;
    const int* dst = ei + E;
    float* out = (float*)d_out;

    // workspace carve-out (256B aligned)
    char* ws = (char*)d_ws;
    size_t off = 0;
    auto carve = [&](size_t bytes) {
        void* p = ws + off;
        off = (off + bytes + 255) & ~(size_t)255;
        return p;
    };
    int*   deg     = (int*)carve((size_t)N * 4);
    float* invdeg  = (float*)carve((size_t)N * 4);
    int*   offsets = (int*)carve(((size_t)N + 1) * 4);
    int*   cursor  = (int*)carve((size_t)N * 4);
    int*   bsum    = (int*)carve(256 * 4);
    int*   adj     = (int*)carve((size_t)E * 4);

    hipMemsetAsync(deg, 0, (size_t)N * 4, stream);
    hipMemsetAsync(cursor, 0, (size_t)N * 4, stream);

    const int TB = 256;
    const int grid_e = MIN((E + TB - 1) / TB, 2048);
    k_deg<<<grid_e, TB, 0, stream>>>(dst, E, deg);
    k_invdeg<<<(N + TB - 1) / TB, TB, 0, stream>>>(deg, invdeg, N);

    const int nb = (N + 1023) / 1024;   // 98 for N=100000, must be <= 256
    k_scan1<<<nb, 1024, 0, stream>>>(deg, offsets, bsum, N);
    k_scan2<<<1, 256, 0, stream>>>(bsum, nb);
    k_scan3<<<nb, 1024, 0, stream>>>(offsets, bsum, deg, N);

    k_build<<<grid_e, TB, 0, stream>>>(src, dst, E, offsets, cursor, adj);

    const int n4 = N * 128 / 4;
    k_copy<<<MIN((n4 + TB - 1) / TB, 2048), TB, 0, stream>>>((const float4*)x, (float4*)out, n4);

    const size_t layer_sz = (size_t)N * 128;
    for (int l = 1; l <= 3; ++l) {
        const float* hin = out + (size_t)(l - 1) * layer_sz;
        float* hout = out + (size_t)l * layer_sz;
        k_layer<<<(N + 3) / 4, TB, 0, stream>>>(hin, hout, adj, offsets, invdeg, N);
    }
}

// Round 2
// 548.363 us; speedup vs baseline: 1.2365x; 1.2365x over previous
//
#include <hip/hip_runtime.h>

#ifndef MIN
#define MIN(a,b) ((a)<(b)?(a):(b))
#endif

// ---------------- degree count ----------------
__global__ void k_deg(const int* __restrict__ dst, int E, int* __restrict__ deg) {
    int i = blockIdx.x * blockDim.x + threadIdx.x;
    int stride = gridDim.x * blockDim.x;
    for (; i < E; i += stride) atomicAdd(&deg[dst[i]], 1);
}

// ---------------- inv_deg = 1/(deg+1) ----------------
__global__ void k_invdeg(const int* __restrict__ deg, float* __restrict__ invdeg, int N) {
    int i = blockIdx.x * blockDim.x + threadIdx.x;
    if (i < N) invdeg[i] = 1.0f / (float)(deg[i] + 1);
}

// ---------------- exclusive scan (3-kernel hierarchical) ----------------
__global__ void k_scan1(const int* __restrict__ deg, int* __restrict__ offsets,
                        int* __restrict__ bsum, int N) {
    __shared__ int sm[1024];
    int i = blockIdx.x * 1024 + threadIdx.x;
    int v = (i < N) ? deg[i] : 0;
    sm[threadIdx.x] = v;
    __syncthreads();
    for (int off = 1; off < 1024; off <<= 1) {
        int t = (threadIdx.x >= off) ? sm[threadIdx.x - off] : 0;
        __syncthreads();
        sm[threadIdx.x] += t;
        __syncthreads();
    }
    if (i < N) offsets[i] = sm[threadIdx.x] - v;       // exclusive within block
    if (threadIdx.x == 1023) bsum[blockIdx.x] = sm[1023];
}

__global__ void k_scan2(int* __restrict__ bsum, int nb) {
    __shared__ int sm[256];
    int v = (threadIdx.x < nb) ? bsum[threadIdx.x] : 0;
    sm[threadIdx.x] = v;
    __syncthreads();
    for (int off = 1; off < 256; off <<= 1) {
        int t = (threadIdx.x >= off) ? sm[threadIdx.x - off] : 0;
        __syncthreads();
        sm[threadIdx.x] += t;
        __syncthreads();
    }
    if (threadIdx.x < nb) bsum[threadIdx.x] = sm[threadIdx.x] - v;  // exclusive
}

__global__ void k_scan3(int* __restrict__ offsets, const int* __restrict__ bsum,
                        const int* __restrict__ deg, int N) {
    int i = blockIdx.x * 1024 + threadIdx.x;
    if (i < N) {
        offsets[i] += bsum[blockIdx.x];
        if (i == N - 1) offsets[N] = offsets[i] + deg[i];
    }
}

// ---------------- build CSR adjacency (by dst) ----------------
__global__ void k_build(const int* __restrict__ src, const int* __restrict__ dst, int E,
                        const int* __restrict__ offsets, int* __restrict__ cursor,
                        int* __restrict__ adj) {
    int i = blockIdx.x * blockDim.x + threadIdx.x;
    int stride = gridDim.x * blockDim.x;
    for (; i < E; i += stride) {
        int d = dst[i];
        int p = atomicAdd(&cursor[d], 1);
        adj[offsets[d] + p] = src[i];
    }
}

// ---------------- layer 0 copy ----------------
__global__ void k_copy(const float4* __restrict__ in, float4* __restrict__ out, int n4) {
    int i = blockIdx.x * blockDim.x + threadIdx.x;
    int stride = gridDim.x * blockDim.x;
    for (; i < n4; i += stride) out[i] = in[i];
}

// ---------------- aggregation layer: one wave (64 lanes) per node ----------------
// lane l owns features [2l, 2l+1] as a float2; D = 128 fixed.
// Edge loop unrolled x8: 8 adjacency loads then 8 independent row gathers in
// flight per wave -> 8x memory-level parallelism vs serial chain.
__global__ void __launch_bounds__(256) k_layer(
        const float* __restrict__ hin, float* __restrict__ hout,
        const int* __restrict__ adj, const int* __restrict__ offsets,
        const float* __restrict__ invdeg, int N) {
    int wave = (blockIdx.x * blockDim.x + threadIdx.x) >> 6;
    int lane = threadIdx.x & 63;
    if (wave >= N) return;
    const int node = wave;
    const int beg = offsets[node];
    const int end = offsets[node + 1];
    const float2* __restrict__ hin2 = (const float2*)hin;
    float2 acc = hin2[(size_t)node * 64 + lane];  // self (self-loop)
    float2 acc2 = make_float2(0.f, 0.f);

    int e = beg;
    for (; e + 8 <= end; e += 8) {
        int s0 = adj[e + 0], s1 = adj[e + 1], s2 = adj[e + 2], s3 = adj[e + 3];
        int s4 = adj[e + 4], s5 = adj[e + 5], s6 = adj[e + 6], s7 = adj[e + 7];
        float2 v0 = hin2[(size_t)s0 * 64 + lane];
        float2 v1 = hin2[(size_t)s1 * 64 + lane];
        float2 v2 = hin2[(size_t)s2 * 64 + lane];
        float2 v3 = hin2[(size_t)s3 * 64 + lane];
        float2 v4 = hin2[(size_t)s4 * 64 + lane];
        float2 v5 = hin2[(size_t)s5 * 64 + lane];
        float2 v6 = hin2[(size_t)s6 * 64 + lane];
        float2 v7 = hin2[(size_t)s7 * 64 + lane];
        acc.x += v0.x + v1.x; acc.y += v0.y + v1.y;
        acc2.x += v2.x + v3.x; acc2.y += v2.y + v3.y;
        acc.x += v4.x + v5.x; acc.y += v4.y + v5.y;
        acc2.x += v6.x + v7.x; acc2.y += v6.y + v7.y;
    }
    for (; e + 2 <= end; e += 2) {
        int s0 = adj[e + 0], s1 = adj[e + 1];
        float2 v0 = hin2[(size_t)s0 * 64 + lane];
        float2 v1 = hin2[(size_t)s1 * 64 + lane];
        acc.x += v0.x; acc.y += v0.y;
        acc2.x += v1.x; acc2.y += v1.y;
    }
    if (e < end) {
        int s = adj[e];
        float2 v = hin2[(size_t)s * 64 + lane];
        acc.x += v.x; acc.y += v.y;
    }
    float w = invdeg[node];
    float2 r;
    r.x = (acc.x + acc2.x) * w;
    r.y = (acc.y + acc2.y) * w;
    ((float2*)hout)[(size_t)node * 64 + lane] = r;
}

extern "C" void kernel_launch(void* const* d_in, const int* in_sizes, int n_in,
                              void* d_out, int out_size, void* d_ws, size_t ws_size,
                              hipStream_t stream) {
    const float* x = (const float*)d_in[0];
    const int* ei = (const int*)d_in[1];
    const int N = in_sizes[0] / 128;   // D = 128
    const int E = in_sizes[1] / 2;
    const int* src = ei;
    const int* dst = ei + E;
    float* out = (float*)d_out;

    // workspace carve-out (256B aligned)
    char* ws = (char*)d_ws;
    size_t off = 0;
    auto carve = [&](size_t bytes) {
        void* p = ws + off;
        off = (off + bytes + 255) & ~(size_t)255;
        return p;
    };
    int*   deg     = (int*)carve((size_t)N * 4);
    float* invdeg  = (float*)carve((size_t)N * 4);
    int*   offsets = (int*)carve(((size_t)N + 1) * 4);
    int*   cursor  = (int*)carve((size_t)N * 4);
    int*   bsum    = (int*)carve(256 * 4);
    int*   adj     = (int*)carve((size_t)E * 4);

    hipMemsetAsync(deg, 0, (size_t)N * 4, stream);
    hipMemsetAsync(cursor, 0, (size_t)N * 4, stream);

    const int TB = 256;
    const int grid_e = MIN((E + TB - 1) / TB, 2048);
    k_deg<<<grid_e, TB, 0, stream>>>(dst, E, deg);
    k_invdeg<<<(N + TB - 1) / TB, TB, 0, stream>>>(deg, invdeg, N);

    const int nb = (N + 1023) / 1024;   // 98 for N=100000, must be <= 256
    k_scan1<<<nb, 1024, 0, stream>>>(deg, offsets, bsum, N);
    k_scan2<<<1, 256, 0, stream>>>(bsum, nb);
    k_scan3<<<nb, 1024, 0, stream>>>(offsets, bsum, deg, N);

    k_build<<<grid_e, TB, 0, stream>>>(src, dst, E, offsets, cursor, adj);

    const int n4 = N * 128 / 4;
    k_copy<<<MIN((n4 + TB - 1) / TB, 2048), TB, 0, stream>>>((const float4*)x, (float4*)out, n4);

    const size_t layer_sz = (size_t)N * 128;
    for (int l = 1; l <= 3; ++l) {
        const float* hin = out + (size_t)(l - 1) * layer_sz;
        float* hout = out + (size_t)l * layer_sz;
        k_layer<<<(N + 3) / 4, TB, 0, stream>>>(hin, hout, adj, offsets, invdeg, N);
    }
}

// Round 3
// 411.858 us; speedup vs baseline: 1.6464x; 1.3314x over previous
//
#include <hip/hip_runtime.h>
#include <hip/hip_fp16.h>

#ifndef MIN
#define MIN(a,b) ((a)<(b)?(a):(b))
#endif

// ---------------- degree count ----------------
__global__ void k_deg(const int* __restrict__ dst, int E, int* __restrict__ deg) {
    int i = blockIdx.x * blockDim.x + threadIdx.x;
    int stride = gridDim.x * blockDim.x;
    for (; i < E; i += stride) atomicAdd(&deg[dst[i]], 1);
}

// ---------------- exclusive scan (3-kernel hierarchical) ----------------
__global__ void k_scan1(const int* __restrict__ deg, int* __restrict__ offsets,
                        int* __restrict__ bsum, int N) {
    __shared__ int sm[1024];
    int i = blockIdx.x * 1024 + threadIdx.x;
    int v = (i < N) ? deg[i] : 0;
    sm[threadIdx.x] = v;
    __syncthreads();
    for (int off = 1; off < 1024; off <<= 1) {
        int t = (threadIdx.x >= off) ? sm[threadIdx.x - off] : 0;
        __syncthreads();
        sm[threadIdx.x] += t;
        __syncthreads();
    }
    if (i < N) offsets[i] = sm[threadIdx.x] - v;       // exclusive within block
    if (threadIdx.x == 1023) bsum[blockIdx.x] = sm[1023];
}

__global__ void k_scan2(int* __restrict__ bsum, int nb) {
    __shared__ int sm[256];
    int v = (threadIdx.x < nb) ? bsum[threadIdx.x] : 0;
    sm[threadIdx.x] = v;
    __syncthreads();
    for (int off = 1; off < 256; off <<= 1) {
        int t = (threadIdx.x >= off) ? sm[threadIdx.x - off] : 0;
        __syncthreads();
        sm[threadIdx.x] += t;
        __syncthreads();
    }
    if (threadIdx.x < nb) bsum[threadIdx.x] = sm[threadIdx.x] - v;  // exclusive
}

__global__ void k_scan3(int* __restrict__ offsets, const int* __restrict__ bsum, int N) {
    int i = blockIdx.x * 1024 + threadIdx.x;
    if (i < N) offsets[i] += bsum[blockIdx.x];
}

// ---------------- build CSR adjacency (by dst), in-place cursor ----------------
// After this kernel, offsets[d] == original exclusive offsets[d+1], i.e.
// node d's slice is [ (d==0?0:offsets[d-1]), offsets[d] ).
__global__ void k_build(const int* __restrict__ src, const int* __restrict__ dst, int E,
                        int* __restrict__ offsets, int* __restrict__ adj) {
    int i = blockIdx.x * blockDim.x + threadIdx.x;
    int stride = gridDim.x * blockDim.x;
    for (; i < E; i += stride) {
        int d = dst[i];
        int p = atomicAdd(&offsets[d], 1);
        adj[p] = src[i];
    }
}

// ---------------- layer 0: copy x -> out (f32) and build f16 gather table ----
__global__ void k_init(const float2* __restrict__ x2, float2* __restrict__ out2,
                       __half2* __restrict__ t2, int n2) {
    int i = blockIdx.x * blockDim.x + threadIdx.x;
    int stride = gridDim.x * blockDim.x;
    for (; i < n2; i += stride) {
        float2 v = x2[i];
        out2[i] = v;
        t2[i] = __floats2half2_rn(v.x, v.y);
    }
}

// ---------------- aggregation layer: one wave (64 lanes) per node ----------------
// Gather table is fp16: row = 128*2B = 256B, lane l owns features [2l,2l+1] as
// __half2 (4B/lane, 256B/wave-instruction). f32 accumulate. Unroll x8 for MLP.
// Writes f32 row to d_out and (optionally) f16 row for the next layer.
__global__ void __launch_bounds__(256) k_layer(
        const __half2* __restrict__ hin, float2* __restrict__ hout,
        __half2* __restrict__ tout, const int* __restrict__ adj,
        const int* __restrict__ offsets, int N) {
    int wave = (blockIdx.x * blockDim.x + threadIdx.x) >> 6;
    int lane = threadIdx.x & 63;
    if (wave >= N) return;
    const int node = wave;
    const int beg = (node == 0) ? 0 : offsets[node - 1];
    const int end = offsets[node];

    __half2 sv = hin[(size_t)node * 64 + lane];       // self (self-loop)
    float ax = __low2float(sv), ay = __high2float(sv);
    float bx = 0.f, by = 0.f;

    int e = beg;
    for (; e + 8 <= end; e += 8) {
        int s0 = adj[e + 0], s1 = adj[e + 1], s2 = adj[e + 2], s3 = adj[e + 3];
        int s4 = adj[e + 4], s5 = adj[e + 5], s6 = adj[e + 6], s7 = adj[e + 7];
        __half2 v0 = hin[(size_t)s0 * 64 + lane];
        __half2 v1 = hin[(size_t)s1 * 64 + lane];
        __half2 v2 = hin[(size_t)s2 * 64 + lane];
        __half2 v3 = hin[(size_t)s3 * 64 + lane];
        __half2 v4 = hin[(size_t)s4 * 64 + lane];
        __half2 v5 = hin[(size_t)s5 * 64 + lane];
        __half2 v6 = hin[(size_t)s6 * 64 + lane];
        __half2 v7 = hin[(size_t)s7 * 64 + lane];
        ax += __low2float(v0) + __low2float(v1);
        ay += __high2float(v0) + __high2float(v1);
        bx += __low2float(v2) + __low2float(v3);
        by += __high2float(v2) + __high2float(v3);
        ax += __low2float(v4) + __low2float(v5);
        ay += __high2float(v4) + __high2float(v5);
        bx += __low2float(v6) + __low2float(v7);
        by += __high2float(v6) + __high2float(v7);
    }
    for (; e + 2 <= end; e += 2) {
        int s0 = adj[e + 0], s1 = adj[e + 1];
        __half2 v0 = hin[(size_t)s0 * 64 + lane];
        __half2 v1 = hin[(size_t)s1 * 64 + lane];
        ax += __low2float(v0); ay += __high2float(v0);
        bx += __low2float(v1); by += __high2float(v1);
    }
    if (e < end) {
        __half2 v = hin[(size_t)adj[e] * 64 + lane];
        ax += __low2float(v); ay += __high2float(v);
    }

    const float w = 1.0f / (float)(end - beg + 1);    // 1/(deg+1)
    float2 r;
    r.x = (ax + bx) * w;
    r.y = (ay + by) * w;
    hout[(size_t)node * 64 + lane] = r;
    if (tout) tout[(size_t)node * 64 + lane] = __floats2half2_rn(r.x, r.y);
}

extern "C" void kernel_launch(void* const* d_in, const int* in_sizes, int n_in,
                              void* d_out, int out_size, void* d_ws, size_t ws_size,
                              hipStream_t stream) {
    const float* x = (const float*)d_in[0];
    const int* ei = (const int*)d_in[1];
    const int N = in_sizes[0] / 128;   // D = 128
    const int E = in_sizes[1] / 2;
    const int* src = ei;
    const int* dst = ei + E;
    float* out = (float*)d_out;

    // workspace carve-out (256B aligned)
    char* ws = (char*)d_ws;
    size_t off = 0;
    auto carve = [&](size_t bytes) {
        void* p = ws + off;
        off = (off + bytes + 255) & ~(size_t)255;
        return p;
    };
    int*     deg     = (int*)carve((size_t)N * 4);
    int*     offsets = (int*)carve(((size_t)N + 1) * 4);
    int*     bsum    = (int*)carve(256 * 4);
    int*     adj     = (int*)carve((size_t)E * 4);
    __half2* tab0    = (__half2*)carve((size_t)N * 64 * 4);   // fp16 table ping
    __half2* tab1    = (__half2*)carve((size_t)N * 64 * 4);   // fp16 table pong

    hipMemsetAsync(deg, 0, (size_t)N * 4, stream);

    const int TB = 256;
    const int grid_e = MIN((E + TB - 1) / TB, 2048);
    k_deg<<<grid_e, TB, 0, stream>>>(dst, E, deg);

    const int nb = (N + 1023) / 1024;   // 98 for N=100000, must be <= 256
    k_scan1<<<nb, 1024, 0, stream>>>(deg, offsets, bsum, N);
    k_scan2<<<1, 256, 0, stream>>>(bsum, nb);
    k_scan3<<<nb, 1024, 0, stream>>>(offsets, bsum, N);

    k_build<<<grid_e, TB, 0, stream>>>(src, dst, E, offsets, adj);

    const int n2 = N * 64;   // half2 / float2 elements per layer
    k_init<<<MIN((n2 + TB - 1) / TB, 2048), TB, 0, stream>>>(
        (const float2*)x, (float2*)out, tab0, n2);

    const size_t layer_sz = (size_t)N * 128;
    __half2* tabs[2] = { tab0, tab1 };
    for (int l = 1; l <= 3; ++l) {
        float* hout = out + (size_t)l * layer_sz;
        __half2* tin = tabs[(l - 1) & 1];
        __half2* tnext = (l < 3) ? tabs[l & 1] : (__half2*)nullptr;
        k_layer<<<(N + 3) / 4, TB, 0, stream>>>(tin, (float2*)hout, tnext, adj, offsets, N);
    }
}

// Round 4
// 282.857 us; speedup vs baseline: 2.3972x; 1.4561x over previous
//
#include <hip/hip_runtime.h>
#include <hip/hip_fp16.h>

#ifndef MIN
#define MIN(a,b) ((a)<(b)?(a):(b))
#endif

// Bucketing: bucket = dst >> BSHIFT, 512 nodes/bucket, K = ceil(N/512) <= 256.
#define BSHIFT 9
#define NB1 256          // blocks in histogram pass
#define TILE 4096        // edges per B3 block
#define B4CAP 12288      // LDS adj capacity per bucket (avg ~8163, max ~8600)

// ---------------- B1: per-block bucket histogram (LDS, no global atomics) ---
__global__ void __launch_bounds__(256) k_hist(const int* __restrict__ dst, int E,
                                              unsigned* __restrict__ partial) {
    __shared__ unsigned c[256];
    int t = threadIdx.x;
    c[t] = 0;
    __syncthreads();
    int i = blockIdx.x * blockDim.x + t;
    int stride = gridDim.x * blockDim.x;
    for (; i < E; i += stride) atomicAdd(&c[((unsigned)dst[i]) >> BSHIFT], 1);
    __syncthreads();
    partial[blockIdx.x * 256 + t] = c[t];
}

// ---------------- B2: reduce partials, scan -> bucket bases/cursors ---------
__global__ void __launch_bounds__(256) k_bscan(const unsigned* __restrict__ partial,
                                               int K, unsigned* __restrict__ bcnt,
                                               unsigned* __restrict__ bbase,
                                               unsigned* __restrict__ gcur,
                                               int* __restrict__ offs, int N, int E) {
    __shared__ unsigned sm[256];
    int t = threadIdx.x;
    unsigned s = 0;
    if (t < K)
        for (int blk = 0; blk < NB1; ++blk) s += partial[blk * 256 + t];
    sm[t] = (t < K) ? s : 0;
    __syncthreads();
    unsigned v = sm[t];
    for (int off = 1; off < 256; off <<= 1) {
        unsigned x = (t >= off) ? sm[t - off] : 0;
        __syncthreads();
        sm[t] += x;
        __syncthreads();
    }
    unsigned excl = sm[t] - v;
    if (t < K) {
        bcnt[t] = s;
        bbase[t] = excl;
        gcur[t] = excl;
    }
    if (t == 0) offs[N] = E;
}

// ---------------- B3: multisplit — tile-local sort by bucket, coalesced out -
__global__ void __launch_bounds__(256) k_split(const int* __restrict__ src,
                                               const int* __restrict__ dst, int E,
                                               unsigned* __restrict__ gcur,
                                               uint2* __restrict__ pairs) {
    __shared__ uint2 sp[TILE];            // 32 KB
    __shared__ unsigned cnt[256], sscan[256], gb[256];
    int t = threadIdx.x;
    int base = blockIdx.x * TILE;
    cnt[t] = 0;
    __syncthreads();

    unsigned pk[TILE / 256];
    #pragma unroll
    for (int j = 0; j < TILE / 256; ++j) {
        int i = base + j * 256 + t;
        if (i < E) {
            unsigned b = ((unsigned)dst[i]) >> BSHIFT;
            unsigned r = atomicAdd(&cnt[b], 1);
            pk[j] = (b << 16) | r;        // r < 4096, b < 256
        } else {
            pk[j] = 0xFFFFFFFFu;
        }
    }
    __syncthreads();

    // exclusive scan of cnt -> sscan
    unsigned v = cnt[t];
    sscan[t] = v;
    __syncthreads();
    for (int off = 1; off < 256; off <<= 1) {
        unsigned x = (t >= off) ? sscan[t - off] : 0;
        __syncthreads();
        sscan[t] += x;
        __syncthreads();
    }
    sscan[t] -= v;
    __syncthreads();

    // local scatter into bucket-sorted order
    #pragma unroll
    for (int j = 0; j < TILE / 256; ++j) {
        if (pk[j] != 0xFFFFFFFFu) {
            int i = base + j * 256 + t;
            unsigned b = pk[j] >> 16, r = pk[j] & 0xFFFFu;
            sp[sscan[b] + r] = make_uint2((unsigned)src[i], (unsigned)dst[i]);
        }
    }
    __syncthreads();

    // one global claim per non-empty bucket
    unsigned n = cnt[t];
    gb[t] = n ? atomicAdd(&gcur[t], n) : 0u;
    __syncthreads();

    // coalesced write-out in bucket-run order
    int cntTile = MIN(TILE, E - base);
    #pragma unroll
    for (int j = 0; j < TILE / 256; ++j) {
        int p = j * 256 + t;
        if (p < cntTile) {
            uint2 e = sp[p];
            unsigned b = e.y >> BSHIFT;
            pairs[gb[b] + (unsigned)p - sscan[b]] = e;
        }
    }
}

// ---------------- B4: per-bucket CSR build fully in LDS, coalesced out ------
__global__ void __launch_bounds__(512) k_csr(const uint2* __restrict__ pairs,
                                             const unsigned* __restrict__ bcnt,
                                             const unsigned* __restrict__ bbase,
                                             int* __restrict__ adj,
                                             int* __restrict__ offs, int N) {
    __shared__ unsigned adjL[B4CAP];      // 48 KB
    __shared__ unsigned cnt[512], cnt2[512], sc[512];
    int t = threadIdx.x;
    int b = blockIdx.x;
    unsigned nb = bcnt[b];
    unsigned bb = bbase[b];
    cnt[t] = 0;
    cnt2[t] = 0;
    __syncthreads();

    for (unsigned i = t; i < nb; i += 512)
        atomicAdd(&cnt[pairs[bb + i].y & 511u], 1);
    __syncthreads();

    // exclusive scan of per-node counts
    unsigned v = cnt[t];
    sc[t] = v;
    __syncthreads();
    for (int off = 1; off < 512; off <<= 1) {
        unsigned x = (t >= off) ? sc[t - off] : 0;
        __syncthreads();
        sc[t] += x;
        __syncthreads();
    }
    sc[t] -= v;
    __syncthreads();

    int node = (b << BSHIFT) + t;
    if (node < N) offs[node] = (int)(bb + sc[t]);

    if (nb <= B4CAP) {
        for (unsigned i = t; i < nb; i += 512) {
            uint2 e = pairs[bb + i];
            unsigned dl = e.y & 511u;
            unsigned pos = sc[dl] + atomicAdd(&cnt2[dl], 1);
            adjL[pos] = e.x;
        }
        __syncthreads();
        for (unsigned i = t; i < nb; i += 512) adj[bb + i] = (int)adjL[i];
    } else {  // statistical impossibility fallback, kept for safety
        for (unsigned i = t; i < nb; i += 512) {
            uint2 e = pairs[bb + i];
            unsigned dl = e.y & 511u;
            unsigned pos = sc[dl] + atomicAdd(&cnt2[dl], 1);
            adj[bb + pos] = (int)e.x;
        }
    }
}

// ---------------- layer 0: copy x -> out (f32) and build f16 gather table ----
__global__ void k_init(const float2* __restrict__ x2, float2* __restrict__ out2,
                       __half2* __restrict__ t2, int n2) {
    int i = blockIdx.x * blockDim.x + threadIdx.x;
    int stride = gridDim.x * blockDim.x;
    for (; i < n2; i += stride) {
        float2 v = x2[i];
        out2[i] = v;
        t2[i] = __floats2half2_rn(v.x, v.y);
    }
}

// ---------------- aggregation layer: one wave per node, fp16 gathers --------
__global__ void __launch_bounds__(256) k_layer(
        const __half2* __restrict__ hin, float2* __restrict__ hout,
        __half2* __restrict__ tout, const int* __restrict__ adj,
        const int* __restrict__ offs, int N) {
    int wave = (blockIdx.x * blockDim.x + threadIdx.x) >> 6;
    int lane = threadIdx.x & 63;
    if (wave >= N) return;
    const int node = wave;
    const int beg = offs[node];
    const int end = offs[node + 1];

    __half2 sv = hin[(size_t)node * 64 + lane];       // self (self-loop)
    float ax = __low2float(sv), ay = __high2float(sv);
    float bx = 0.f, by = 0.f;

    int e = beg;
    for (; e + 16 <= end; e += 16) {
        int s[16];
        #pragma unroll
        for (int j = 0; j < 16; ++j) s[j] = adj[e + j];
        __half2 v[16];
        #pragma unroll
        for (int j = 0; j < 16; ++j) v[j] = hin[(size_t)s[j] * 64 + lane];
        #pragma unroll
        for (int j = 0; j < 16; j += 4) {
            ax += __low2float(v[j]) + __low2float(v[j + 1]);
            ay += __high2float(v[j]) + __high2float(v[j + 1]);
            bx += __low2float(v[j + 2]) + __low2float(v[j + 3]);
            by += __high2float(v[j + 2]) + __high2float(v[j + 3]);
        }
    }
    for (; e + 8 <= end; e += 8) {
        int s[8];
        #pragma unroll
        for (int j = 0; j < 8; ++j) s[j] = adj[e + j];
        __half2 v[8];
        #pragma unroll
        for (int j = 0; j < 8; ++j) v[j] = hin[(size_t)s[j] * 64 + lane];
        #pragma unroll
        for (int j = 0; j < 8; j += 4) {
            ax += __low2float(v[j]) + __low2float(v[j + 1]);
            ay += __high2float(v[j]) + __high2float(v[j + 1]);
            bx += __low2float(v[j + 2]) + __low2float(v[j + 3]);
            by += __high2float(v[j + 2]) + __high2float(v[j + 3]);
        }
    }
    for (; e + 2 <= end; e += 2) {
        __half2 v0 = hin[(size_t)adj[e] * 64 + lane];
        __half2 v1 = hin[(size_t)adj[e + 1] * 64 + lane];
        ax += __low2float(v0); ay += __high2float(v0);
        bx += __low2float(v1); by += __high2float(v1);
    }
    if (e < end) {
        __half2 v = hin[(size_t)adj[e] * 64 + lane];
        ax += __low2float(v); ay += __high2float(v);
    }

    const float w = 1.0f / (float)(end - beg + 1);    // 1/(deg+1)
    float2 r;
    r.x = (ax + bx) * w;
    r.y = (ay + by) * w;
    hout[(size_t)node * 64 + lane] = r;
    if (tout) tout[(size_t)node * 64 + lane] = __floats2half2_rn(r.x, r.y);
}

extern "C" void kernel_launch(void* const* d_in, const int* in_sizes, int n_in,
                              void* d_out, int out_size, void* d_ws, size_t ws_size,
                              hipStream_t stream) {
    const float* x = (const float*)d_in[0];
    const int* ei = (const int*)d_in[1];
    const int N = in_sizes[0] / 128;   // D = 128
    const int E = in_sizes[1] / 2;
    const int* src = ei;
    const int* dst = ei + E;
    float* out = (float*)d_out;
    const int K = (N + 511) >> BSHIFT; // buckets (196 for N=100000)

    // workspace carve-out (256B aligned)
    char* ws = (char*)d_ws;
    size_t off = 0;
    auto carve = [&](size_t bytes) {
        void* p = ws + off;
        off = (off + bytes + 255) & ~(size_t)255;
        return p;
    };
    unsigned* partial = (unsigned*)carve((size_t)NB1 * 256 * 4);
    unsigned* bcnt    = (unsigned*)carve(256 * 4);
    unsigned* bbase   = (unsigned*)carve(256 * 4);
    unsigned* gcur    = (unsigned*)carve(256 * 4);
    int*      offs    = (int*)carve(((size_t)N + 1) * 4);
    uint2*    pairs   = (uint2*)carve((size_t)E * 8);
    int*      adj     = (int*)carve((size_t)E * 4);
    __half2*  tab0    = (__half2*)carve((size_t)N * 64 * 4);
    __half2*  tab1    = (__half2*)carve((size_t)N * 64 * 4);

    k_hist<<<NB1, 256, 0, stream>>>(dst, E, partial);
    k_bscan<<<1, 256, 0, stream>>>(partial, K, bcnt, bbase, gcur, offs, N, E);
    k_split<<<(E + TILE - 1) / TILE, 256, 0, stream>>>(src, dst, E, gcur, pairs);
    k_csr<<<K, 512, 0, stream>>>(pairs, bcnt, bbase, adj, offs, N);

    const int n2 = N * 64;   // half2 / float2 elements per layer
    k_init<<<MIN((n2 + 255) / 256, 2048), 256, 0, stream>>>(
        (const float2*)x, (float2*)out, tab0, n2);

    const size_t layer_sz = (size_t)N * 128;
    __half2* tabs[2] = { tab0, tab1 };
    for (int l = 1; l <= 3; ++l) {
        float* hout = out + (size_t)l * layer_sz;
        __half2* tin = tabs[(l - 1) & 1];
        __half2* tnext = (l < 3) ? tabs[l & 1] : (__half2*)nullptr;
        k_layer<<<(N + 3) / 4, 256, 0, stream>>>(tin, (float2*)hout, tnext, adj, offs, N);
    }
}

// Round 5
// 233.838 us; speedup vs baseline: 2.8997x; 1.2096x over previous
//
#include <hip/hip_runtime.h>
#include <hip/hip_fp16.h>

#ifndef MIN
#define MIN(a,b) ((a)<(b)?(a):(b))
#endif

// Bucketing: bucket = dst >> BSHIFT, 512 nodes/bucket, K = ceil(N/512) <= 256.
#define BSHIFT 9
#define NB1 256          // blocks in histogram pass
#define TILE 4096        // edges per B3 block
#define B4CAP 12288      // LDS adj capacity per bucket (avg ~8163, max ~8600)

typedef float floatx2 __attribute__((ext_vector_type(2)));

#if defined(__has_builtin)
#if __has_builtin(__builtin_amdgcn_cvt_pk_f32_fp8) && __has_builtin(__builtin_amdgcn_cvt_pk_fp8_f32)
#define HW_FP8 1
#endif
#endif

// ---- fp8 e4m3 (OCP) pair decode/encode; HW path on gfx950 ----
__device__ __forceinline__ floatx2 fp8x2_dec(unsigned short v) {
#ifdef HW_FP8
    return __builtin_amdgcn_cvt_pk_f32_fp8((int)(unsigned)v, false);
#else
    floatx2 r;
    unsigned b0 = v & 0xFFu, b1 = (v >> 8) & 0xFFu;
    float f0 = __uint_as_float(((b0 & 0x80u) << 24) | ((b0 & 0x7Fu) << 20));
    float f1 = __uint_as_float(((b1 & 0x80u) << 24) | ((b1 & 0x7Fu) << 20));
    r.x = f0 * 1.329227995784916e+36f;   // 2^120
    r.y = f1 * 1.329227995784916e+36f;
    return r;
#endif
}

__device__ __forceinline__ unsigned short fp8x2_enc(float x, float y) {
#ifdef HW_FP8
    int p = __builtin_amdgcn_cvt_pk_fp8_f32(x, y, 0, false);
    return (unsigned short)((unsigned)p & 0xFFFFu);
#else
    auto enc1 = [](float f) -> unsigned {
        float yv = f * 7.52316384526264e-37f;   // 2^-120
        unsigned u = __float_as_uint(yv);
        unsigned s = (u >> 24) & 0x80u;
        unsigned em = u & 0x7FFFFFFFu;
        unsigned keep = em >> 20;
        unsigned rem = em & 0xFFFFFu;
        keep += (rem > 0x80000u || (rem == 0x80000u && (keep & 1u))) ? 1u : 0u;
        if (keep > 0x7Fu) keep = 0x7Fu;
        return s | keep;
    };
    return (unsigned short)(enc1(x) | (enc1(y) << 8));
#endif
}

// ---------------- B1: per-block bucket histogram (LDS, no global atomics) ---
__global__ void __launch_bounds__(256) k_hist(const int* __restrict__ dst, int E,
                                              unsigned* __restrict__ partial) {
    __shared__ unsigned c[256];
    int t = threadIdx.x;
    c[t] = 0;
    __syncthreads();
    int i = blockIdx.x * blockDim.x + t;
    int stride = gridDim.x * blockDim.x;
    for (; i < E; i += stride) atomicAdd(&c[((unsigned)dst[i]) >> BSHIFT], 1);
    __syncthreads();
    partial[blockIdx.x * 256 + t] = c[t];
}

// ---------------- B2: reduce partials, scan -> bucket bases/cursors ---------
__global__ void __launch_bounds__(256) k_bscan(const unsigned* __restrict__ partial,
                                               int K, unsigned* __restrict__ bcnt,
                                               unsigned* __restrict__ bbase,
                                               unsigned* __restrict__ gcur,
                                               int* __restrict__ offs, int N, int E) {
    __shared__ unsigned sm[256];
    int t = threadIdx.x;
    unsigned s = 0;
    if (t < K)
        for (int blk = 0; blk < NB1; ++blk) s += partial[blk * 256 + t];
    sm[t] = (t < K) ? s : 0;
    __syncthreads();
    unsigned v = sm[t];
    for (int off = 1; off < 256; off <<= 1) {
        unsigned x = (t >= off) ? sm[t - off] : 0;
        __syncthreads();
        sm[t] += x;
        __syncthreads();
    }
    unsigned excl = sm[t] - v;
    if (t < K) {
        bcnt[t] = s;
        bbase[t] = excl;
        gcur[t] = excl;
    }
    if (t == 0) offs[N] = E;
}

// ---------------- B3: multisplit — tile-local sort by bucket, coalesced out -
__global__ void __launch_bounds__(256) k_split(const int* __restrict__ src,
                                               const int* __restrict__ dst, int E,
                                               unsigned* __restrict__ gcur,
                                               uint2* __restrict__ pairs) {
    __shared__ uint2 sp[TILE];            // 32 KB
    __shared__ unsigned cnt[256], sscan[256], gb[256];
    int t = threadIdx.x;
    int base = blockIdx.x * TILE;
    cnt[t] = 0;
    __syncthreads();

    unsigned pk[TILE / 256];
    #pragma unroll
    for (int j = 0; j < TILE / 256; ++j) {
        int i = base + j * 256 + t;
        if (i < E) {
            unsigned b = ((unsigned)dst[i]) >> BSHIFT;
            unsigned r = atomicAdd(&cnt[b], 1);
            pk[j] = (b << 16) | r;        // r < 4096, b < 256
        } else {
            pk[j] = 0xFFFFFFFFu;
        }
    }
    __syncthreads();

    // exclusive scan of cnt -> sscan
    unsigned v = cnt[t];
    sscan[t] = v;
    __syncthreads();
    for (int off = 1; off < 256; off <<= 1) {
        unsigned x = (t >= off) ? sscan[t - off] : 0;
        __syncthreads();
        sscan[t] += x;
        __syncthreads();
    }
    sscan[t] -= v;
    __syncthreads();

    // local scatter into bucket-sorted order
    #pragma unroll
    for (int j = 0; j < TILE / 256; ++j) {
        if (pk[j] != 0xFFFFFFFFu) {
            int i = base + j * 256 + t;
            unsigned b = pk[j] >> 16, r = pk[j] & 0xFFFFu;
            sp[sscan[b] + r] = make_uint2((unsigned)src[i], (unsigned)dst[i]);
        }
    }
    __syncthreads();

    // one global claim per non-empty bucket
    unsigned n = cnt[t];
    gb[t] = n ? atomicAdd(&gcur[t], n) : 0u;
    __syncthreads();

    // coalesced write-out in bucket-run order
    int cntTile = MIN(TILE, E - base);
    #pragma unroll
    for (int j = 0; j < TILE / 256; ++j) {
        int p = j * 256 + t;
        if (p < cntTile) {
            uint2 e = sp[p];
            unsigned b = e.y >> BSHIFT;
            pairs[gb[b] + (unsigned)p - sscan[b]] = e;
        }
    }
}

// ---------------- B4: per-bucket CSR build fully in LDS, coalesced out ------
__global__ void __launch_bounds__(512) k_csr(const uint2* __restrict__ pairs,
                                             const unsigned* __restrict__ bcnt,
                                             const unsigned* __restrict__ bbase,
                                             int* __restrict__ adj,
                                             int* __restrict__ offs, int N) {
    __shared__ unsigned adjL[B4CAP];      // 48 KB
    __shared__ unsigned cnt[512], cnt2[512], sc[512];
    int t = threadIdx.x;
    int b = blockIdx.x;
    unsigned nb = bcnt[b];
    unsigned bb = bbase[b];
    cnt[t] = 0;
    cnt2[t] = 0;
    __syncthreads();

    for (unsigned i = t; i < nb; i += 512)
        atomicAdd(&cnt[pairs[bb + i].y & 511u], 1);
    __syncthreads();

    // exclusive scan of per-node counts
    unsigned v = cnt[t];
    sc[t] = v;
    __syncthreads();
    for (int off = 1; off < 512; off <<= 1) {
        unsigned x = (t >= off) ? sc[t - off] : 0;
        __syncthreads();
        sc[t] += x;
        __syncthreads();
    }
    sc[t] -= v;
    __syncthreads();

    int node = (b << BSHIFT) + t;
    if (node < N) offs[node] = (int)(bb + sc[t]);

    if (nb <= B4CAP) {
        for (unsigned i = t; i < nb; i += 512) {
            uint2 e = pairs[bb + i];
            unsigned dl = e.y & 511u;
            unsigned pos = sc[dl] + atomicAdd(&cnt2[dl], 1);
            adjL[pos] = e.x;
        }
        __syncthreads();
        for (unsigned i = t; i < nb; i += 512) adj[bb + i] = (int)adjL[i];
    } else {  // statistical impossibility fallback, kept for safety
        for (unsigned i = t; i < nb; i += 512) {
            uint2 e = pairs[bb + i];
            unsigned dl = e.y & 511u;
            unsigned pos = sc[dl] + atomicAdd(&cnt2[dl], 1);
            adj[bb + pos] = (int)e.x;
        }
    }
}

// ---------------- layer 0: copy x -> out (f32) and build fp8 gather table ---
__global__ void k_init(const float2* __restrict__ x2, float2* __restrict__ out2,
                       unsigned short* __restrict__ t8, int n2) {
    int i = blockIdx.x * blockDim.x + threadIdx.x;
    int stride = gridDim.x * blockDim.x;
    for (; i < n2; i += stride) {
        float2 v = x2[i];
        out2[i] = v;
        t8[i] = fp8x2_enc(v.x, v.y);
    }
}

// ---------------- aggregation layer: one wave per node, fp8 gathers ---------
// Gather table is fp8 e4m3: row = 128 B, lane l owns features [2l,2l+1] as a
// ushort (2 B/lane, 128 B/wave-gather). f32 accumulate. Unroll x16 for MLP.
__global__ void __launch_bounds__(256) k_layer(
        const unsigned short* __restrict__ hin, float2* __restrict__ hout,
        unsigned short* __restrict__ tout, const int* __restrict__ adj,
        const int* __restrict__ offs, int N) {
    int wave = (blockIdx.x * blockDim.x + threadIdx.x) >> 6;
    int lane = threadIdx.x & 63;
    if (wave >= N) return;
    const int node = wave;
    const int beg = offs[node];
    const int end = offs[node + 1];

    floatx2 sf = fp8x2_dec(hin[(size_t)node * 64 + lane]);   // self (self-loop)
    float ax = sf.x, ay = sf.y;
    float bx = 0.f, by = 0.f;

    int e = beg;
    for (; e + 16 <= end; e += 16) {
        int s[16];
        #pragma unroll
        for (int j = 0; j < 16; ++j) s[j] = adj[e + j];
        unsigned short v[16];
        #pragma unroll
        for (int j = 0; j < 16; ++j) v[j] = hin[(size_t)s[j] * 64 + lane];
        #pragma unroll
        for (int j = 0; j < 16; j += 2) {
            floatx2 f0 = fp8x2_dec(v[j]);
            floatx2 f1 = fp8x2_dec(v[j + 1]);
            ax += f0.x; ay += f0.y;
            bx += f1.x; by += f1.y;
        }
    }
    for (; e + 8 <= end; e += 8) {
        int s[8];
        #pragma unroll
        for (int j = 0; j < 8; ++j) s[j] = adj[e + j];
        unsigned short v[8];
        #pragma unroll
        for (int j = 0; j < 8; ++j) v[j] = hin[(size_t)s[j] * 64 + lane];
        #pragma unroll
        for (int j = 0; j < 8; j += 2) {
            floatx2 f0 = fp8x2_dec(v[j]);
            floatx2 f1 = fp8x2_dec(v[j + 1]);
            ax += f0.x; ay += f0.y;
            bx += f1.x; by += f1.y;
        }
    }
    for (; e + 2 <= end; e += 2) {
        unsigned short v0 = hin[(size_t)adj[e] * 64 + lane];
        unsigned short v1 = hin[(size_t)adj[e + 1] * 64 + lane];
        floatx2 f0 = fp8x2_dec(v0);
        floatx2 f1 = fp8x2_dec(v1);
        ax += f0.x; ay += f0.y;
        bx += f1.x; by += f1.y;
    }
    if (e < end) {
        floatx2 f = fp8x2_dec(hin[(size_t)adj[e] * 64 + lane]);
        ax += f.x; ay += f.y;
    }

    const float w = 1.0f / (float)(end - beg + 1);    // 1/(deg+1)
    float2 r;
    r.x = (ax + bx) * w;
    r.y = (ay + by) * w;
    hout[(size_t)node * 64 + lane] = r;
    if (tout) tout[(size_t)node * 64 + lane] = fp8x2_enc(r.x, r.y);
}

extern "C" void kernel_launch(void* const* d_in, const int* in_sizes, int n_in,
                              void* d_out, int out_size, void* d_ws, size_t ws_size,
                              hipStream_t stream) {
    const float* x = (const float*)d_in[0];
    const int* ei = (const int*)d_in[1];
    const int N = in_sizes[0] / 128;   // D = 128
    const int E = in_sizes[1] / 2;
    const int* src = ei;
    const int* dst = ei + E;
    float* out = (float*)d_out;
    const int K = (N + 511) >> BSHIFT; // buckets (196 for N=100000)

    // workspace carve-out (256B aligned)
    char* ws = (char*)d_ws;
    size_t off = 0;
    auto carve = [&](size_t bytes) {
        void* p = ws + off;
        off = (off + bytes + 255) & ~(size_t)255;
        return p;
    };
    unsigned* partial = (unsigned*)carve((size_t)NB1 * 256 * 4);
    unsigned* bcnt    = (unsigned*)carve(256 * 4);
    unsigned* bbase   = (unsigned*)carve(256 * 4);
    unsigned* gcur    = (unsigned*)carve(256 * 4);
    int*      offs    = (int*)carve(((size_t)N + 1) * 4);
    uint2*    pairs   = (uint2*)carve((size_t)E * 8);
    int*      adj     = (int*)carve((size_t)E * 4);
    unsigned short* tab0 = (unsigned short*)carve((size_t)N * 64 * 2);  // fp8 ping
    unsigned short* tab1 = (unsigned short*)carve((size_t)N * 64 * 2);  // fp8 pong

    k_hist<<<NB1, 256, 0, stream>>>(dst, E, partial);
    k_bscan<<<1, 256, 0, stream>>>(partial, K, bcnt, bbase, gcur, offs, N, E);
    k_split<<<(E + TILE - 1) / TILE, 256, 0, stream>>>(src, dst, E, gcur, pairs);
    k_csr<<<K, 512, 0, stream>>>(pairs, bcnt, bbase, adj, offs, N);

    const int n2 = N * 64;   // ushort / float2 elements per layer
    k_init<<<MIN((n2 + 255) / 256, 2048), 256, 0, stream>>>(
        (const float2*)x, (float2*)out, tab0, n2);

    const size_t layer_sz = (size_t)N * 128;
    unsigned short* tabs[2] = { tab0, tab1 };
    for (int l = 1; l <= 3; ++l) {
        float* hout = out + (size_t)l * layer_sz;
        unsigned short* tin = tabs[(l - 1) & 1];
        unsigned short* tnext = (l < 3) ? tabs[l & 1] : (unsigned short*)nullptr;
        k_layer<<<(N + 3) / 4, 256, 0, stream>>>(tin, (float2*)hout, tnext, adj, offs, N);
    }
}